// Round 2
// baseline (1804.190 us; speedup 1.0000x reference)
//
#include <hip/hip_runtime.h>
#include <hip/hip_bf16.h>
#include <cstdint>
#include <cstddef>

#define B 64
#define T 512
#define EMBED 128
#define H 128
#define G4 512          // 4*H
#define HOUT 256        // 2*H (bilstm concat)
#define NUM_CLASSES 10
#define BT (B * T)      // 32768

// ---------------------------------------------------------------------------
// 1) gather: A0[row, :] = emb[x[row], :]
// ---------------------------------------------------------------------------
__global__ __launch_bounds__(EMBED) void gather_kernel(
    const int* __restrict__ x, const float* __restrict__ emb,
    float* __restrict__ A0)
{
    int row = blockIdx.x;
    int tok = x[row];
    A0[(size_t)row * EMBED + threadIdx.x] = emb[(size_t)tok * EMBED + threadIdx.x];
}

// ---------------------------------------------------------------------------
// 2) GEMM: C(M,G4) = A(M,K) @ W(K,G4) + bias(G4)
//    BM=128, BN=64, BK=16, 256 threads, 8x4 micro-tile
// ---------------------------------------------------------------------------
#define BM 128
#define BN 64
#define BK 16

__global__ __launch_bounds__(256) void gemm_bias_kernel(
    const float* __restrict__ A, const float* __restrict__ W,
    const float* __restrict__ bias, float* __restrict__ C, int K)
{
    __shared__ __align__(16) float As[BK][BM + 4];  // transposed: As[k][m]
    __shared__ __align__(16) float Ws[BK][BN + 4];  // Ws[k][n]

    int tid = threadIdx.x;
    int tx = tid & 15;    // N direction, 16 x 4 = 64
    int ty = tid >> 4;    // M direction, 16 x 8 = 128
    int m0 = blockIdx.y * BM;
    int n0 = blockIdx.x * BN;

    float acc[8][4];
#pragma unroll
    for (int i = 0; i < 8; i++)
#pragma unroll
        for (int j = 0; j < 4; j++) acc[i][j] = 0.f;

    for (int k0 = 0; k0 < K; k0 += BK) {
        // A tile: 128 rows x 16 k = 512 float4, 2 per thread (store transposed)
#pragma unroll
        for (int i = 0; i < 2; i++) {
            int idx = tid + i * 256;          // 0..511
            int r   = idx >> 2;               // 0..127
            int cq  = idx & 3;                // float4 slot in k
            float4 a = *(const float4*)&A[(size_t)(m0 + r) * K + k0 + cq * 4];
            As[cq * 4 + 0][r] = a.x;
            As[cq * 4 + 1][r] = a.y;
            As[cq * 4 + 2][r] = a.z;
            As[cq * 4 + 3][r] = a.w;
        }
        // W tile: 16 k x 64 n = 256 float4, 1 per thread
        {
            int rw = tid >> 4;                // 0..15
            int cq = tid & 15;
            float4 wv = *(const float4*)&W[(size_t)(k0 + rw) * G4 + n0 + cq * 4];
            *(float4*)&Ws[rw][cq * 4] = wv;
        }
        __syncthreads();

#pragma unroll
        for (int k = 0; k < BK; k++) {
            float4 a0 = *(const float4*)&As[k][ty * 8];
            float4 a1 = *(const float4*)&As[k][ty * 8 + 4];
            float4 w0 = *(const float4*)&Ws[k][tx * 4];
            float av[8] = {a0.x, a0.y, a0.z, a0.w, a1.x, a1.y, a1.z, a1.w};
            float wv[4] = {w0.x, w0.y, w0.z, w0.w};
#pragma unroll
            for (int i = 0; i < 8; i++)
#pragma unroll
                for (int j = 0; j < 4; j++)
                    acc[i][j] = fmaf(av[i], wv[j], acc[i][j]);
        }
        __syncthreads();
    }

    float4 bv = *(const float4*)&bias[n0 + tx * 4];
#pragma unroll
    for (int i = 0; i < 8; i++) {
        int m = m0 + ty * 8 + i;
        float4 o;
        o.x = acc[i][0] + bv.x;
        o.y = acc[i][1] + bv.y;
        o.z = acc[i][2] + bv.z;
        o.w = acc[i][3] + bv.w;
        *(float4*)&C[(size_t)m * G4 + n0 + tx * 4] = o;
    }
}

// ---------------------------------------------------------------------------
// 3) LSTM scan v2: one WG (1024 threads, 16 waves) per (batch, direction).
//    tid = (q<<3) | (half<<2) | g : column q in [0,128), k-half, gate g.
//    Thread computes z-partial for z-column col = g*128+q over k in
//    [half*64, half*64+64) with weights in 16 float4 VGPRs.
//    z combine: shfl_xor(4); gate exchange: quad-local shfl_xor(1,2,3) (DPP).
//    One barrier per step, double-buffered h in LDS.
// ---------------------------------------------------------------------------
__device__ __forceinline__ float fast_sig(float x) {
    // 1/(1+e^-x); inf-safe: e=inf -> rcp(inf)=0
    float e = __expf(-x);
    return __builtin_amdgcn_rcpf(1.f + e);
}

__global__ __launch_bounds__(1024, 4) void lstm_scan_kernel(
    const float* __restrict__ xp0, const float* __restrict__ xp1,
    const float* __restrict__ Wh0, const float* __restrict__ Wh1,
    const int* __restrict__ x, float* __restrict__ hout)
{
    const int b   = blockIdx.x;
    const int dir = blockIdx.y;  // 0 = forward, 1 = reverse
    const float* __restrict__ xp = dir ? xp1 : xp0;
    const float* __restrict__ Wh = dir ? Wh1 : Wh0;

    const int tid  = threadIdx.x;
    const int g    = tid & 3;            // gate 0..3 (i,f,g,o)
    const int half = (tid >> 2) & 1;     // k-half
    const int q    = tid >> 3;           // hidden column 0..127
    const int col  = g * H + q;          // z-column 0..511
    const int kb   = half * 64;

    // recurrent weights for (col, k in [kb, kb+64)) -> 16 float4 VGPRs
    float4 wv[16];
#pragma unroll
    for (int kk = 0; kk < 16; kk++) {
        wv[kk].x = Wh[(size_t)(kb + 4 * kk + 0) * G4 + col];
        wv[kk].y = Wh[(size_t)(kb + 4 * kk + 1) * G4 + col];
        wv[kk].z = Wh[(size_t)(kb + 4 * kk + 2) * G4 + col];
        wv[kk].w = Wh[(size_t)(kb + 4 * kk + 3) * G4 + col];
    }

    __shared__ __align__(16) float h_sh[2][H];
    __shared__ unsigned char mask_sh[T];

    if (tid < H) { h_sh[0][tid] = 0.f; h_sh[1][tid] = 0.f; }
    if (tid < T) mask_sh[tid] = (x[(size_t)b * T + tid] != 0) ? 1 : 0;
    float c_reg = 0.f, h_reg = 0.f;
    __syncthreads();

    int rb = 0;
    float xp_next = (half == 0)
        ? xp[((size_t)b * T + (dir ? T - 1 : 0)) * G4 + col] : 0.f;

    for (int s = 0; s < T; s++) {
        const int t = dir ? (T - 1 - s) : s;
        float xcur = xp_next;
        if (half == 0 && s + 1 < T) {  // prefetch next step's xp
            int tn = dir ? (T - 2 - s) : (s + 1);
            xp_next = xp[((size_t)b * T + tn) * G4 + col];
        }

        // matvec partial: 64 FMAs, 4 accumulators, broadcast LDS reads
        const float4* hp = (const float4*)&h_sh[rb][kb];
        float a0 = 0.f, a1 = 0.f, a2 = 0.f, a3 = 0.f;
#pragma unroll
        for (int kk = 0; kk < 16; kk++) {
            float4 h4 = hp[kk];
            a0 = fmaf(h4.x, wv[kk].x, a0);
            a1 = fmaf(h4.y, wv[kk].y, a1);
            a2 = fmaf(h4.z, wv[kk].z, a2);
            a3 = fmaf(h4.w, wv[kk].w, a3);
        }
        float part = ((a0 + a1) + (a2 + a3)) + xcur;
        float z = part + __shfl_xor(part, 4);   // combine k-halves

        // my gate's activation: sig for i,f,o ; tanh(z) = 2*sig(2z)-1 for g
        float zz  = (g == 2) ? (z + z) : z;
        float S   = fast_sig(zz);
        float act = (g == 2) ? (2.f * S - 1.f) : S;

        // exchange activations within the quad (all DPP)
        float b1 = __shfl_xor(act, 1);
        float b2 = __shfl_xor(act, 2);
        float b3 = __shfl_xor(act, 3);
        // val at xor-distance d from me: 0->act,1->b1,2->b2,3->b3
        int dI = g, dF = g ^ 1, dG = g ^ 2, dO = g ^ 3;
        float ig = (dI & 2) ? ((dI & 1) ? b3 : b2) : ((dI & 1) ? b1 : act);
        float fg = (dF & 2) ? ((dF & 1) ? b3 : b2) : ((dF & 1) ? b1 : act);
        float gg = (dG & 2) ? ((dG & 1) ? b3 : b2) : ((dG & 1) ? b1 : act);
        float og = (dO & 2) ? ((dO & 1) ? b3 : b2) : ((dO & 1) ? b1 : act);

        float cn = fmaf(fg, c_reg, ig * gg);
        // tanh(cn) = 2*sig(2*cn)-1 (inf-safe at extremes)
        float th = 2.f * fast_sig(cn + cn) - 1.f;
        float hn = og * th;

        if (mask_sh[t]) { c_reg = cn; h_reg = hn; }

        if ((tid & 7) == 0) {  // one lane per column: g=0, half=0
            h_sh[rb ^ 1][q] = h_reg;
            hout[((size_t)b * T + t) * HOUT + dir * H + q] = h_reg;
        }
        __syncthreads();
        rb ^= 1;
    }
}

// ---------------------------------------------------------------------------
// 4) pooling: per (b,t) max & mean over 256 channels -> feat (B, 2T)
// ---------------------------------------------------------------------------
__global__ __launch_bounds__(256) void pool_kernel(
    const float* __restrict__ Hin, float* __restrict__ feat)
{
    int wave = threadIdx.x >> 6;
    int lane = threadIdx.x & 63;
    int bt = blockIdx.x * 4 + wave;
    float4 v = *(const float4*)&Hin[(size_t)bt * HOUT + lane * 4];
    float mx = fmaxf(fmaxf(v.x, v.y), fmaxf(v.z, v.w));
    float sm = (v.x + v.y) + (v.z + v.w);
#pragma unroll
    for (int off = 32; off > 0; off >>= 1) {
        mx = fmaxf(mx, __shfl_down(mx, off));
        sm += __shfl_down(sm, off);
    }
    if (lane == 0) {
        int b = bt >> 9;        // /T
        int t = bt & (T - 1);
        feat[(size_t)b * (2 * T) + t]     = mx;
        feat[(size_t)b * (2 * T) + T + t] = sm * (1.f / 256.f);
    }
}

// ---------------------------------------------------------------------------
// 5) FC: out(B,10) = relu(feat(B,1024) @ fcW(1024,10) + fcb)
// ---------------------------------------------------------------------------
__global__ __launch_bounds__(128) void fc_kernel(
    const float* __restrict__ feat, const float* __restrict__ fcW,
    const float* __restrict__ fcb, float* __restrict__ out)
{
    __shared__ float red[2][NUM_CLASSES];
    int b = blockIdx.x, tid = threadIdx.x;
    float acc[NUM_CLASSES];
#pragma unroll
    for (int c = 0; c < NUM_CLASSES; c++) acc[c] = 0.f;
#pragma unroll
    for (int it = 0; it < 8; it++) {
        int k = tid + it * 128;
        float fv = feat[(size_t)b * 1024 + k];
#pragma unroll
        for (int c = 0; c < NUM_CLASSES; c++)
            acc[c] = fmaf(fv, fcW[(size_t)k * NUM_CLASSES + c], acc[c]);
    }
#pragma unroll
    for (int c = 0; c < NUM_CLASSES; c++) {
        float v = acc[c];
        for (int off = 32; off > 0; off >>= 1) v += __shfl_down(v, off);
        if ((tid & 63) == 0) red[tid >> 6][c] = v;
    }
    __syncthreads();
    if (tid < NUM_CLASSES) {
        float v = red[0][tid] + red[1][tid] + fcb[tid];
        out[(size_t)b * NUM_CLASSES + tid] = fmaxf(v, 0.f);
    }
}

// ---------------------------------------------------------------------------
// launch
// ---------------------------------------------------------------------------
extern "C" void kernel_launch(void* const* d_in, const int* in_sizes, int n_in,
                              void* d_out, int out_size, void* d_ws, size_t ws_size,
                              hipStream_t stream)
{
    const int*   x     = (const int*)d_in[0];
    const float* emb   = (const float*)d_in[1];
    const float* Wx_f0 = (const float*)d_in[2];
    const float* Wh_f0 = (const float*)d_in[3];
    const float* b_f0  = (const float*)d_in[4];
    const float* Wx_b0 = (const float*)d_in[5];
    const float* Wh_b0 = (const float*)d_in[6];
    const float* b_b0  = (const float*)d_in[7];
    const float* Wx_f1 = (const float*)d_in[8];
    const float* Wh_f1 = (const float*)d_in[9];
    const float* b_f1  = (const float*)d_in[10];
    const float* Wx_b1 = (const float*)d_in[11];
    const float* Wh_b1 = (const float*)d_in[12];
    const float* b_b1  = (const float*)d_in[13];
    const float* fcW   = (const float*)d_in[14];
    const float* fcb   = (const float*)d_in[15];
    float* out = (float*)d_out;

    char* ws = (char*)d_ws;
    const size_t MB = 1024 * 1024;
    // A0 [0,16MB) is dead after the layer-0 GEMMs; H1 overlays [0,32MB).
    float* A0   = (float*)(ws);                  // 16 MB  (BT x 128)
    float* H1   = (float*)(ws);                  // 32 MB  (BT x 256) - overlaps A0
    float* H0   = (float*)(ws + 32 * MB);        // 32 MB  (BT x 256)
    float* xpF  = (float*)(ws + 64 * MB);        // 64 MB  (BT x 512)
    float* xpB  = (float*)(ws + 128 * MB);       // 64 MB  (BT x 512)
    float* feat = (float*)(ws + 192 * MB);       // 256 KB (B x 1024)

    dim3 ggrid(G4 / BN, BT / BM);  // (8, 256)

    // layer 0
    gather_kernel<<<BT, EMBED, 0, stream>>>(x, emb, A0);
    gemm_bias_kernel<<<ggrid, 256, 0, stream>>>(A0, Wx_f0, b_f0, xpF, EMBED);
    gemm_bias_kernel<<<ggrid, 256, 0, stream>>>(A0, Wx_b0, b_b0, xpB, EMBED);
    lstm_scan_kernel<<<dim3(B, 2), 1024, 0, stream>>>(xpF, xpB, Wh_f0, Wh_b0, x, H0);

    // layer 1 (input = H0, K = 256)
    gemm_bias_kernel<<<ggrid, 256, 0, stream>>>(H0, Wx_f1, b_f1, xpF, 2 * H);
    gemm_bias_kernel<<<ggrid, 256, 0, stream>>>(H0, Wx_b1, b_b1, xpB, 2 * H);
    lstm_scan_kernel<<<dim3(B, 2), 1024, 0, stream>>>(xpF, xpB, Wh_f1, Wh_b1, x, H1);

    // pooling + FC
    pool_kernel<<<BT / 4, 256, 0, stream>>>(H1, feat);
    fc_kernel<<<B, 128, 0, stream>>>(feat, fcW, fcb, out);
}

// Round 3
// 1346.163 us; speedup vs baseline: 1.3402x; 1.3402x over previous
//
#include <hip/hip_runtime.h>
#include <hip/hip_bf16.h>
#include <cstdint>
#include <cstddef>

#define B 64
#define T 512
#define EMBED 128
#define H 128
#define G4 512          // 4*H
#define HOUT 256        // 2*H (bilstm concat)
#define NUM_CLASSES 10
#define BT (B * T)      // 32768

// ---------------------------------------------------------------------------
// 1) GEMM: C(M,G4) = A(M,K) @ W(K,G4) + bias(G4)
//    BM=128, BN=64, BK=16, 256 threads, 8x4 micro-tile.
//    If xrow != nullptr, A-row m is A[xrow[m], :] (embedding fusion).
// ---------------------------------------------------------------------------
#define BM 128
#define BN 64
#define BK 16

__global__ __launch_bounds__(256) void gemm_bias_kernel(
    const float* __restrict__ A, const int* __restrict__ xrow,
    const float* __restrict__ W, const float* __restrict__ bias,
    float* __restrict__ C, int K)
{
    __shared__ __align__(16) float As[BK][BM + 4];  // transposed: As[k][m]
    __shared__ __align__(16) float Ws[BK][BN + 4];  // Ws[k][n]

    int tid = threadIdx.x;
    int tx = tid & 15;    // N direction, 16 x 4 = 64
    int ty = tid >> 4;    // M direction, 16 x 8 = 128
    int m0 = blockIdx.y * BM;
    int n0 = blockIdx.x * BN;

    // A-row pointers for this thread's two staging rows (fixed across k-tiles)
    int ra = tid >> 2;        // 0..63
    int cq = tid & 3;         // float4 slot in k
    const float* arow0;
    const float* arow1;
    if (xrow) {
        arow0 = A + (size_t)xrow[m0 + ra] * K;
        arow1 = A + (size_t)xrow[m0 + ra + 64] * K;
    } else {
        arow0 = A + (size_t)(m0 + ra) * K;
        arow1 = A + (size_t)(m0 + ra + 64) * K;
    }

    float acc[8][4];
#pragma unroll
    for (int i = 0; i < 8; i++)
#pragma unroll
        for (int j = 0; j < 4; j++) acc[i][j] = 0.f;

    for (int k0 = 0; k0 < K; k0 += BK) {
        // A tile: 128 rows x 16 k (store transposed)
        {
            float4 a = *(const float4*)&arow0[k0 + cq * 4];
            As[cq * 4 + 0][ra] = a.x;
            As[cq * 4 + 1][ra] = a.y;
            As[cq * 4 + 2][ra] = a.z;
            As[cq * 4 + 3][ra] = a.w;
            float4 b = *(const float4*)&arow1[k0 + cq * 4];
            As[cq * 4 + 0][ra + 64] = b.x;
            As[cq * 4 + 1][ra + 64] = b.y;
            As[cq * 4 + 2][ra + 64] = b.z;
            As[cq * 4 + 3][ra + 64] = b.w;
        }
        // W tile: 16 k x 64 n = 256 float4, 1 per thread
        {
            int rw = tid >> 4;                // 0..15
            int cw = tid & 15;
            float4 wv = *(const float4*)&W[(size_t)(k0 + rw) * G4 + n0 + cw * 4];
            *(float4*)&Ws[rw][cw * 4] = wv;
        }
        __syncthreads();

#pragma unroll
        for (int k = 0; k < BK; k++) {
            float4 a0 = *(const float4*)&As[k][ty * 8];
            float4 a1 = *(const float4*)&As[k][ty * 8 + 4];
            float4 w0 = *(const float4*)&Ws[k][tx * 4];
            float av[8] = {a0.x, a0.y, a0.z, a0.w, a1.x, a1.y, a1.z, a1.w};
            float wv[4] = {w0.x, w0.y, w0.z, w0.w};
#pragma unroll
            for (int i = 0; i < 8; i++)
#pragma unroll
                for (int j = 0; j < 4; j++)
                    acc[i][j] = fmaf(av[i], wv[j], acc[i][j]);
        }
        __syncthreads();
    }

    float4 bv = *(const float4*)&bias[n0 + tx * 4];
#pragma unroll
    for (int i = 0; i < 8; i++) {
        int m = m0 + ty * 8 + i;
        float4 o;
        o.x = acc[i][0] + bv.x;
        o.y = acc[i][1] + bv.y;
        o.z = acc[i][2] + bv.z;
        o.w = acc[i][3] + bv.w;
        *(float4*)&C[(size_t)m * G4 + n0 + tx * 4] = o;
    }
}

// ---------------------------------------------------------------------------
// 2) LSTM scan v3: one WG (1024 threads, 16 waves) per (batch, direction).
//    tid = (q<<3) | (half<<2) | g. Weights: 16 NAMED float4 (no array ->
//    guaranteed registers; waves_per_eu(4,4) gives the 128-VGPR budget).
//    h partitioned into two skewed half-buffers (+4 floats) so the wave's
//    two ds_read addresses hit disjoint bank groups -> conflict-free.
//    One barrier per step (double-buffered h).
// ---------------------------------------------------------------------------
__device__ __forceinline__ float fast_sig(float x) {
    // 1/(1+e^-x); inf-safe: e=inf -> rcp(inf)=0
    float e = __expf(-x);
    return __builtin_amdgcn_rcpf(1.f + e);
}

__global__ __launch_bounds__(1024) __attribute__((amdgpu_waves_per_eu(4, 4)))
void lstm_scan_kernel(
    const float* __restrict__ xp0, const float* __restrict__ xp1,
    const float* __restrict__ Wh0, const float* __restrict__ Wh1,
    const int* __restrict__ x, float* __restrict__ hout)
{
    const int b   = blockIdx.x;
    const int dir = blockIdx.y;  // 0 = forward, 1 = reverse
    const float* __restrict__ xp = dir ? xp1 : xp0;
    const float* __restrict__ Wh = dir ? Wh1 : Wh0;

    const int tid  = threadIdx.x;
    const int g    = tid & 3;            // gate 0..3 (i,f,g,o)
    const int half = (tid >> 2) & 1;     // k-half
    const int q    = tid >> 3;           // hidden column 0..127
    const int col  = g * H + q;          // z-column 0..511
    const int kb   = half * 64;

    // recurrent weights for (col, k in [kb, kb+64)) -> 16 NAMED float4 regs
    const float* wp = Wh + (size_t)kb * G4 + col;
#define LDW(i) float4 w##i; \
    w##i.x = wp[(4 * i + 0) * G4]; w##i.y = wp[(4 * i + 1) * G4]; \
    w##i.z = wp[(4 * i + 2) * G4]; w##i.w = wp[(4 * i + 3) * G4];
    LDW(0)  LDW(1)  LDW(2)  LDW(3)
    LDW(4)  LDW(5)  LDW(6)  LDW(7)
    LDW(8)  LDW(9)  LDW(10) LDW(11)
    LDW(12) LDW(13) LDW(14) LDW(15)
#undef LDW

    // h: [buf][half][64 data + 4 skew]. bank(base half0)=8rb, half1=8rb+4 ->
    // the wave's two read addresses always hit disjoint 4-bank groups.
    __shared__ __align__(16) float h_sh[2][2][68];
    __shared__ unsigned char mask_sh[T];

    if (tid < 128) h_sh[0][tid >> 6][tid & 63] = 0.f;
    if (tid < T) mask_sh[tid] = (x[(size_t)b * T + tid] != 0) ? 1 : 0;
    float c_reg = 0.f, h_reg = 0.f;
    __syncthreads();

    int rb = 0;
    float xp_next = (half == 0)
        ? xp[((size_t)b * T + (dir ? T - 1 : 0)) * G4 + col] : 0.f;

    for (int s = 0; s < T; s++) {
        const int t = dir ? (T - 1 - s) : s;
        float xcur = xp_next;
        if (half == 0 && s + 1 < T) {  // prefetch next step's xp
            int tn = dir ? (T - 2 - s) : (s + 1);
            xp_next = xp[((size_t)b * T + tn) * G4 + col];
        }

        // matvec partial: 64 FMAs, 4 accumulators, broadcast LDS reads
        const float4* hp = (const float4*)&h_sh[rb][half][0];
        float a0 = 0.f, a1 = 0.f, a2 = 0.f, a3 = 0.f;
#define FMA4(i) { float4 h4 = hp[i]; \
        a0 = fmaf(h4.x, w##i.x, a0); a1 = fmaf(h4.y, w##i.y, a1); \
        a2 = fmaf(h4.z, w##i.z, a2); a3 = fmaf(h4.w, w##i.w, a3); }
        FMA4(0)  FMA4(1)  FMA4(2)  FMA4(3)
        FMA4(4)  FMA4(5)  FMA4(6)  FMA4(7)
        FMA4(8)  FMA4(9)  FMA4(10) FMA4(11)
        FMA4(12) FMA4(13) FMA4(14) FMA4(15)
#undef FMA4
        float part = ((a0 + a1) + (a2 + a3)) + xcur;
        float z = part + __shfl_xor(part, 4);   // combine k-halves

        // my gate's activation: sig for i,f,o ; tanh(z) = 2*sig(2z)-1 for g
        float zz  = (g == 2) ? (z + z) : z;
        float S   = fast_sig(zz);
        float act = (g == 2) ? (2.f * S - 1.f) : S;

        // exchange activations within the quad (all DPP)
        float b1 = __shfl_xor(act, 1);
        float b2 = __shfl_xor(act, 2);
        float b3 = __shfl_xor(act, 3);
        // val at xor-distance d from me: 0->act,1->b1,2->b2,3->b3
        int dI = g, dF = g ^ 1, dG = g ^ 2, dO = g ^ 3;
        float ig = (dI & 2) ? ((dI & 1) ? b3 : b2) : ((dI & 1) ? b1 : act);
        float fg = (dF & 2) ? ((dF & 1) ? b3 : b2) : ((dF & 1) ? b1 : act);
        float gg = (dG & 2) ? ((dG & 1) ? b3 : b2) : ((dG & 1) ? b1 : act);
        float og = (dO & 2) ? ((dO & 1) ? b3 : b2) : ((dO & 1) ? b1 : act);

        float cn = fmaf(fg, c_reg, ig * gg);
        // tanh(cn) = 2*sig(2*cn)-1 (inf-safe at extremes)
        float th = 2.f * fast_sig(cn + cn) - 1.f;
        float hn = og * th;

        if (mask_sh[t]) { c_reg = cn; h_reg = hn; }

        if ((tid & 7) == 0) {  // one lane per column: g=0, half=0
            h_sh[rb ^ 1][q >> 6][q & 63] = h_reg;
            hout[((size_t)b * T + t) * HOUT + dir * H + q] = h_reg;
        }
        __syncthreads();
        rb ^= 1;
    }
}

// ---------------------------------------------------------------------------
// 3) pooling: per (b,t) max & mean over 256 channels -> feat (B, 2T)
// ---------------------------------------------------------------------------
__global__ __launch_bounds__(256) void pool_kernel(
    const float* __restrict__ Hin, float* __restrict__ feat)
{
    int wave = threadIdx.x >> 6;
    int lane = threadIdx.x & 63;
    int bt = blockIdx.x * 4 + wave;
    float4 v = *(const float4*)&Hin[(size_t)bt * HOUT + lane * 4];
    float mx = fmaxf(fmaxf(v.x, v.y), fmaxf(v.z, v.w));
    float sm = (v.x + v.y) + (v.z + v.w);
#pragma unroll
    for (int off = 32; off > 0; off >>= 1) {
        mx = fmaxf(mx, __shfl_down(mx, off));
        sm += __shfl_down(sm, off);
    }
    if (lane == 0) {
        int b = bt >> 9;        // /T
        int t = bt & (T - 1);
        feat[(size_t)b * (2 * T) + t]     = mx;
        feat[(size_t)b * (2 * T) + T + t] = sm * (1.f / 256.f);
    }
}

// ---------------------------------------------------------------------------
// 4) FC: out(B,10) = relu(feat(B,1024) @ fcW(1024,10) + fcb)
// ---------------------------------------------------------------------------
__global__ __launch_bounds__(128) void fc_kernel(
    const float* __restrict__ feat, const float* __restrict__ fcW,
    const float* __restrict__ fcb, float* __restrict__ out)
{
    __shared__ float red[2][NUM_CLASSES];
    int b = blockIdx.x, tid = threadIdx.x;
    float acc[NUM_CLASSES];
#pragma unroll
    for (int c = 0; c < NUM_CLASSES; c++) acc[c] = 0.f;
#pragma unroll
    for (int it = 0; it < 8; it++) {
        int k = tid + it * 128;
        float fv = feat[(size_t)b * 1024 + k];
#pragma unroll
        for (int c = 0; c < NUM_CLASSES; c++)
            acc[c] = fmaf(fv, fcW[(size_t)k * NUM_CLASSES + c], acc[c]);
    }
#pragma unroll
    for (int c = 0; c < NUM_CLASSES; c++) {
        float v = acc[c];
        for (int off = 32; off > 0; off >>= 1) v += __shfl_down(v, off);
        if ((tid & 63) == 0) red[tid >> 6][c] = v;
    }
    __syncthreads();
    if (tid < NUM_CLASSES) {
        float v = red[0][tid] + red[1][tid] + fcb[tid];
        out[(size_t)b * NUM_CLASSES + tid] = fmaxf(v, 0.f);
    }
}

// ---------------------------------------------------------------------------
// launch
// ---------------------------------------------------------------------------
extern "C" void kernel_launch(void* const* d_in, const int* in_sizes, int n_in,
                              void* d_out, int out_size, void* d_ws, size_t ws_size,
                              hipStream_t stream)
{
    const int*   x     = (const int*)d_in[0];
    const float* emb   = (const float*)d_in[1];
    const float* Wx_f0 = (const float*)d_in[2];
    const float* Wh_f0 = (const float*)d_in[3];
    const float* b_f0  = (const float*)d_in[4];
    const float* Wx_b0 = (const float*)d_in[5];
    const float* Wh_b0 = (const float*)d_in[6];
    const float* b_b0  = (const float*)d_in[7];
    const float* Wx_f1 = (const float*)d_in[8];
    const float* Wh_f1 = (const float*)d_in[9];
    const float* b_f1  = (const float*)d_in[10];
    const float* Wx_b1 = (const float*)d_in[11];
    const float* Wh_b1 = (const float*)d_in[12];
    const float* b_b1  = (const float*)d_in[13];
    const float* fcW   = (const float*)d_in[14];
    const float* fcb   = (const float*)d_in[15];
    float* out = (float*)d_out;

    char* ws = (char*)d_ws;
    const size_t MB = 1024 * 1024;
    float* H1   = (float*)(ws);                  // 32 MB  (BT x 256)
    float* H0   = (float*)(ws + 32 * MB);        // 32 MB  (BT x 256)
    float* xpF  = (float*)(ws + 64 * MB);        // 64 MB  (BT x 512)
    float* xpB  = (float*)(ws + 128 * MB);       // 64 MB  (BT x 512)
    float* feat = (float*)(ws + 192 * MB);       // 256 KB (B x 1024)

    dim3 ggrid(G4 / BN, BT / BM);  // (8, 256)

    // layer 0 (A-rows gathered from emb on the fly)
    gemm_bias_kernel<<<ggrid, 256, 0, stream>>>(emb, x, Wx_f0, b_f0, xpF, EMBED);
    gemm_bias_kernel<<<ggrid, 256, 0, stream>>>(emb, x, Wx_b0, b_b0, xpB, EMBED);
    lstm_scan_kernel<<<dim3(B, 2), 1024, 0, stream>>>(xpF, xpB, Wh_f0, Wh_b0, x, H0);

    // layer 1 (input = H0, K = 256)
    gemm_bias_kernel<<<ggrid, 256, 0, stream>>>(H0, nullptr, Wx_f1, b_f1, xpF, 2 * H);
    gemm_bias_kernel<<<ggrid, 256, 0, stream>>>(H0, nullptr, Wx_b1, b_b1, xpB, 2 * H);
    lstm_scan_kernel<<<dim3(B, 2), 1024, 0, stream>>>(xpF, xpB, Wh_f1, Wh_b1, x, H1);

    // pooling + FC
    pool_kernel<<<BT / 4, 256, 0, stream>>>(H1, feat);
    fc_kernel<<<B, 128, 0, stream>>>(feat, fcW, fcb, out);
}

// Round 4
// 1187.523 us; speedup vs baseline: 1.5193x; 1.1336x over previous
//
#include <hip/hip_runtime.h>
#include <hip/hip_bf16.h>
#include <cstdint>
#include <cstddef>

#define B 64
#define T 512
#define EMBED 128
#define H 128
#define G4 512          // 4*H
#define HOUT 256        // 2*H (bilstm concat)
#define NUM_CLASSES 10
#define BT (B * T)      // 32768

// ---------------------------------------------------------------------------
// 1) GEMM: C(M,G4) = A(M,K) @ W(K,G4) + bias(G4)
//    BM=128, BN=64, BK=16, 256 threads, 8x4 micro-tile.
//    If xrow != nullptr, A-row m is A[xrow[m], :] (embedding fusion).
// ---------------------------------------------------------------------------
#define BM 128
#define BN 64
#define BK 16

__global__ __launch_bounds__(256) void gemm_bias_kernel(
    const float* __restrict__ A, const int* __restrict__ xrow,
    const float* __restrict__ W, const float* __restrict__ bias,
    float* __restrict__ C, int K)
{
    __shared__ __align__(16) float As[BK][BM + 4];  // transposed: As[k][m]
    __shared__ __align__(16) float Ws[BK][BN + 4];  // Ws[k][n]

    int tid = threadIdx.x;
    int tx = tid & 15;    // N direction, 16 x 4 = 64
    int ty = tid >> 4;    // M direction, 16 x 8 = 128
    int m0 = blockIdx.y * BM;
    int n0 = blockIdx.x * BN;

    // A-row pointers for this thread's two staging rows (fixed across k-tiles)
    int ra = tid >> 2;        // 0..63
    int cq = tid & 3;         // float4 slot in k
    const float* arow0;
    const float* arow1;
    if (xrow) {
        arow0 = A + (size_t)xrow[m0 + ra] * K;
        arow1 = A + (size_t)xrow[m0 + ra + 64] * K;
    } else {
        arow0 = A + (size_t)(m0 + ra) * K;
        arow1 = A + (size_t)(m0 + ra + 64) * K;
    }

    float acc[8][4];
#pragma unroll
    for (int i = 0; i < 8; i++)
#pragma unroll
        for (int j = 0; j < 4; j++) acc[i][j] = 0.f;

    for (int k0 = 0; k0 < K; k0 += BK) {
        // A tile: 128 rows x 16 k (store transposed)
        {
            float4 a = *(const float4*)&arow0[k0 + cq * 4];
            As[cq * 4 + 0][ra] = a.x;
            As[cq * 4 + 1][ra] = a.y;
            As[cq * 4 + 2][ra] = a.z;
            As[cq * 4 + 3][ra] = a.w;
            float4 b = *(const float4*)&arow1[k0 + cq * 4];
            As[cq * 4 + 0][ra + 64] = b.x;
            As[cq * 4 + 1][ra + 64] = b.y;
            As[cq * 4 + 2][ra + 64] = b.z;
            As[cq * 4 + 3][ra + 64] = b.w;
        }
        // W tile: 16 k x 64 n = 256 float4, 1 per thread
        {
            int rw = tid >> 4;                // 0..15
            int cw = tid & 15;
            float4 wv = *(const float4*)&W[(size_t)(k0 + rw) * G4 + n0 + cw * 4];
            *(float4*)&Ws[rw][cw * 4] = wv;
        }
        __syncthreads();

#pragma unroll
        for (int k = 0; k < BK; k++) {
            float4 a0 = *(const float4*)&As[k][ty * 8];
            float4 a1 = *(const float4*)&As[k][ty * 8 + 4];
            float4 w0 = *(const float4*)&Ws[k][tx * 4];
            float av[8] = {a0.x, a0.y, a0.z, a0.w, a1.x, a1.y, a1.z, a1.w};
            float wv[4] = {w0.x, w0.y, w0.z, w0.w};
#pragma unroll
            for (int i = 0; i < 8; i++)
#pragma unroll
                for (int j = 0; j < 4; j++)
                    acc[i][j] = fmaf(av[i], wv[j], acc[i][j]);
        }
        __syncthreads();
    }

    float4 bv = *(const float4*)&bias[n0 + tx * 4];
#pragma unroll
    for (int i = 0; i < 8; i++) {
        int m = m0 + ty * 8 + i;
        float4 o;
        o.x = acc[i][0] + bv.x;
        o.y = acc[i][1] + bv.y;
        o.z = acc[i][2] + bv.z;
        o.w = acc[i][3] + bv.w;
        *(float4*)&C[(size_t)m * G4 + n0 + tx * 4] = o;
    }
}

// ---------------------------------------------------------------------------
// 2) LSTM scan v4: one WG (1024 threads, 16 waves) per (batch, direction).
//    tid = q*8 + ks: thread computes partial z for ALL 4 gate columns
//    {c*128+q, c=0..3} over k in [ks*16, ks*16+16).
//    - 64 weight floats pinned in VGPRs via opaque asm (blocks remat).
//    - h in 8 skewed 20-float LDS blocks: the wave's 8 distinct b128
//      addresses partition the 32 banks -> conflict-free, 8-way broadcast.
//    - ks-octet combine: DPP-only butterfly (quad_perm xor1, xor2, then
//      row_half_mirror for quad<->quad, valid since quads are uniform).
//    - gates computed lane-locally (all 8 lanes of q redundant).
//    One barrier per step, double-buffered h.
// ---------------------------------------------------------------------------
__device__ __forceinline__ float fast_sig(float x) {
    // 1/(1+e^-x); inf-safe: e=inf -> rcp(inf)=0
    float e = __expf(-x);
    return __builtin_amdgcn_rcpf(1.f + e);
}

template <int CTRL>
__device__ __forceinline__ float dpp_add(float x) {
    int y = __builtin_amdgcn_mov_dpp(__float_as_int(x), CTRL, 0xF, 0xF, true);
    return x + __int_as_float(y);
}

__global__ __launch_bounds__(1024) __attribute__((amdgpu_waves_per_eu(4, 4)))
void lstm_scan_kernel(
    const float* __restrict__ xp0, const float* __restrict__ xp1,
    const float* __restrict__ Wh0, const float* __restrict__ Wh1,
    const int* __restrict__ x, float* __restrict__ hout)
{
    const int b   = blockIdx.x;
    const int dir = blockIdx.y;  // 0 = forward, 1 = reverse
    const float* __restrict__ xp = dir ? xp1 : xp0;
    const float* __restrict__ Wh = dir ? Wh1 : Wh0;

    const int tid = threadIdx.x;
    const int ks  = tid & 7;     // k-slice 0..7 -> k in [16ks, 16ks+16)
    const int q   = tid >> 3;    // hidden column 0..127

    // weights: Wh[k][c*H+q], k = ks*16 + r  -> 64 named floats, asm-pinned
    const float* wp = Wh + (size_t)(ks * 16) * G4 + q;
#define DECLW(c) \
    float w##c##_0  = wp[c * H +  0 * G4], w##c##_1  = wp[c * H +  1 * G4], \
          w##c##_2  = wp[c * H +  2 * G4], w##c##_3  = wp[c * H +  3 * G4], \
          w##c##_4  = wp[c * H +  4 * G4], w##c##_5  = wp[c * H +  5 * G4], \
          w##c##_6  = wp[c * H +  6 * G4], w##c##_7  = wp[c * H +  7 * G4], \
          w##c##_8  = wp[c * H +  8 * G4], w##c##_9  = wp[c * H +  9 * G4], \
          w##c##_10 = wp[c * H + 10 * G4], w##c##_11 = wp[c * H + 11 * G4], \
          w##c##_12 = wp[c * H + 12 * G4], w##c##_13 = wp[c * H + 13 * G4], \
          w##c##_14 = wp[c * H + 14 * G4], w##c##_15 = wp[c * H + 15 * G4];
    DECLW(0) DECLW(1) DECLW(2) DECLW(3)
#undef DECLW
#define PIN4(a, b_, c_, d_) asm volatile("" : "+v"(a), "+v"(b_), "+v"(c_), "+v"(d_))
#define PINC(c) \
    PIN4(w##c##_0,  w##c##_1,  w##c##_2,  w##c##_3);  \
    PIN4(w##c##_4,  w##c##_5,  w##c##_6,  w##c##_7);  \
    PIN4(w##c##_8,  w##c##_9,  w##c##_10, w##c##_11); \
    PIN4(w##c##_12, w##c##_13, w##c##_14, w##c##_15)
    PINC(0); PINC(1); PINC(2); PINC(3);
#undef PINC
#undef PIN4

    // h: [buf][block ks][16 data + 4 skew]; block bases hit banks
    // {0,20,8,28,16,4,24,12} (mod 32) -> 8 reads partition all banks.
    __shared__ __align__(16) float h_sh[2][8][20];
    __shared__ unsigned char mask_sh[T];

    if (tid < H) h_sh[0][tid >> 4][tid & 15] = 0.f;
    if (tid < T) mask_sh[tid] = (x[(size_t)b * T + tid] != 0) ? 1 : 0;
    float c_reg = 0.f, h_reg = 0.f;
    __syncthreads();

    const int t0 = dir ? T - 1 : 0;
    const ptrdiff_t dstep = dir ? -(ptrdiff_t)G4 : (ptrdiff_t)G4;
    const ptrdiff_t hstep = dir ? -(ptrdiff_t)HOUT : (ptrdiff_t)HOUT;
    // all lanes load (ks&3) -> no exec-masked address OOB, values for ks>=4
    // are discarded by the (ks==c) init selects.
    const float* xptr = xp + ((size_t)b * T + t0) * G4 + (ks & 3) * H + q;
    float*       hptr = hout + ((size_t)b * T + t0) * HOUT + dir * H + q;
    float xp_cur = *xptr;

    int cb = 0;
    int t = t0;
    const int tinc = dir ? -1 : 1;

    for (int s = 0; s < T; s++) {
        float xin = xp_cur;
        if (s + 1 < T) {           // prefetch next step's xp
            xptr += dstep;
            xp_cur = *xptr;
        }

        // partials: a_c = (ks==c ? xp : 0) + sum_r h[16ks+r] * w_c_r
        float a0 = (ks == 0) ? xin : 0.f;
        float a1 = (ks == 1) ? xin : 0.f;
        float a2 = (ks == 2) ? xin : 0.f;
        float a3 = (ks == 3) ? xin : 0.f;

        const float4* hp = (const float4*)&h_sh[cb][ks][0];
        float4 hv0 = hp[0], hv1 = hp[1], hv2 = hp[2], hv3 = hp[3];
#define FMA16(c) \
        a##c = fmaf(hv0.x, w##c##_0,  a##c); a##c = fmaf(hv0.y, w##c##_1,  a##c); \
        a##c = fmaf(hv0.z, w##c##_2,  a##c); a##c = fmaf(hv0.w, w##c##_3,  a##c); \
        a##c = fmaf(hv1.x, w##c##_4,  a##c); a##c = fmaf(hv1.y, w##c##_5,  a##c); \
        a##c = fmaf(hv1.z, w##c##_6,  a##c); a##c = fmaf(hv1.w, w##c##_7,  a##c); \
        a##c = fmaf(hv2.x, w##c##_8,  a##c); a##c = fmaf(hv2.y, w##c##_9,  a##c); \
        a##c = fmaf(hv2.z, w##c##_10, a##c); a##c = fmaf(hv2.w, w##c##_11, a##c); \
        a##c = fmaf(hv3.x, w##c##_12, a##c); a##c = fmaf(hv3.y, w##c##_13, a##c); \
        a##c = fmaf(hv3.z, w##c##_14, a##c); a##c = fmaf(hv3.w, w##c##_15, a##c);
        FMA16(0) FMA16(1) FMA16(2) FMA16(3)
#undef FMA16

        // butterfly over the 8 ks-lanes: xor1, xor2 (quad_perm), then
        // quad<->quad via row_half_mirror (quads uniform after level 2).
        a0 = dpp_add<0xB1>(a0);  a1 = dpp_add<0xB1>(a1);
        a2 = dpp_add<0xB1>(a2);  a3 = dpp_add<0xB1>(a3);
        a0 = dpp_add<0x4E>(a0);  a1 = dpp_add<0x4E>(a1);
        a2 = dpp_add<0x4E>(a2);  a3 = dpp_add<0x4E>(a3);
        a0 = dpp_add<0x141>(a0); a1 = dpp_add<0x141>(a1);
        a2 = dpp_add<0x141>(a2); a3 = dpp_add<0x141>(a3);

        // gates (lane-local, redundant across the octet)
        float ig = fast_sig(a0);
        float fg = fast_sig(a1);
        float gg = 2.f * fast_sig(a2 + a2) - 1.f;   // tanh
        float og = fast_sig(a3);
        float cn = fmaf(fg, c_reg, ig * gg);
        float th = 2.f * fast_sig(cn + cn) - 1.f;   // tanh
        float hn = og * th;

        bool msk = mask_sh[t] != 0;
        c_reg = msk ? cn : c_reg;
        h_reg = msk ? hn : h_reg;

        if (ks == 0) {
            h_sh[cb ^ 1][q >> 4][q & 15] = h_reg;
            *hptr = h_reg;
        }
        hptr += hstep;
        __syncthreads();
        cb ^= 1;
        t += tinc;
    }
}

// ---------------------------------------------------------------------------
// 3) pooling: per (b,t) max & mean over 256 channels -> feat (B, 2T)
// ---------------------------------------------------------------------------
__global__ __launch_bounds__(256) void pool_kernel(
    const float* __restrict__ Hin, float* __restrict__ feat)
{
    int wave = threadIdx.x >> 6;
    int lane = threadIdx.x & 63;
    int bt = blockIdx.x * 4 + wave;
    float4 v = *(const float4*)&Hin[(size_t)bt * HOUT + lane * 4];
    float mx = fmaxf(fmaxf(v.x, v.y), fmaxf(v.z, v.w));
    float sm = (v.x + v.y) + (v.z + v.w);
#pragma unroll
    for (int off = 32; off > 0; off >>= 1) {
        mx = fmaxf(mx, __shfl_down(mx, off));
        sm += __shfl_down(sm, off);
    }
    if (lane == 0) {
        int b = bt >> 9;        // /T
        int t = bt & (T - 1);
        feat[(size_t)b * (2 * T) + t]     = mx;
        feat[(size_t)b * (2 * T) + T + t] = sm * (1.f / 256.f);
    }
}

// ---------------------------------------------------------------------------
// 4) FC: out(B,10) = relu(feat(B,1024) @ fcW(1024,10) + fcb)
// ---------------------------------------------------------------------------
__global__ __launch_bounds__(128) void fc_kernel(
    const float* __restrict__ feat, const float* __restrict__ fcW,
    const float* __restrict__ fcb, float* __restrict__ out)
{
    __shared__ float red[2][NUM_CLASSES];
    int b = blockIdx.x, tid = threadIdx.x;
    float acc[NUM_CLASSES];
#pragma unroll
    for (int c = 0; c < NUM_CLASSES; c++) acc[c] = 0.f;
#pragma unroll
    for (int it = 0; it < 8; it++) {
        int k = tid + it * 128;
        float fv = feat[(size_t)b * 1024 + k];
#pragma unroll
        for (int c = 0; c < NUM_CLASSES; c++)
            acc[c] = fmaf(fv, fcW[(size_t)k * NUM_CLASSES + c], acc[c]);
    }
#pragma unroll
    for (int c = 0; c < NUM_CLASSES; c++) {
        float v = acc[c];
        for (int off = 32; off > 0; off >>= 1) v += __shfl_down(v, off);
        if ((tid & 63) == 0) red[tid >> 6][c] = v;
    }
    __syncthreads();
    if (tid < NUM_CLASSES) {
        float v = red[0][tid] + red[1][tid] + fcb[tid];
        out[(size_t)b * NUM_CLASSES + tid] = fmaxf(v, 0.f);
    }
}

// ---------------------------------------------------------------------------
// launch
// ---------------------------------------------------------------------------
extern "C" void kernel_launch(void* const* d_in, const int* in_sizes, int n_in,
                              void* d_out, int out_size, void* d_ws, size_t ws_size,
                              hipStream_t stream)
{
    const int*   x     = (const int*)d_in[0];
    const float* emb   = (const float*)d_in[1];
    const float* Wx_f0 = (const float*)d_in[2];
    const float* Wh_f0 = (const float*)d_in[3];
    const float* b_f0  = (const float*)d_in[4];
    const float* Wx_b0 = (const float*)d_in[5];
    const float* Wh_b0 = (const float*)d_in[6];
    const float* b_b0  = (const float*)d_in[7];
    const float* Wx_f1 = (const float*)d_in[8];
    const float* Wh_f1 = (const float*)d_in[9];
    const float* b_f1  = (const float*)d_in[10];
    const float* Wx_b1 = (const float*)d_in[11];
    const float* Wh_b1 = (const float*)d_in[12];
    const float* b_b1  = (const float*)d_in[13];
    const float* fcW   = (const float*)d_in[14];
    const float* fcb   = (const float*)d_in[15];
    float* out = (float*)d_out;

    char* ws = (char*)d_ws;
    const size_t MB = 1024 * 1024;
    float* H1   = (float*)(ws);                  // 32 MB  (BT x 256)
    float* H0   = (float*)(ws + 32 * MB);        // 32 MB  (BT x 256)
    float* xpF  = (float*)(ws + 64 * MB);        // 64 MB  (BT x 512)
    float* xpB  = (float*)(ws + 128 * MB);       // 64 MB  (BT x 512)
    float* feat = (float*)(ws + 192 * MB);       // 256 KB (B x 1024)

    dim3 ggrid(G4 / BN, BT / BM);  // (8, 256)

    // layer 0 (A-rows gathered from emb on the fly)
    gemm_bias_kernel<<<ggrid, 256, 0, stream>>>(emb, x, Wx_f0, b_f0, xpF, EMBED);
    gemm_bias_kernel<<<ggrid, 256, 0, stream>>>(emb, x, Wx_b0, b_b0, xpB, EMBED);
    lstm_scan_kernel<<<dim3(B, 2), 1024, 0, stream>>>(xpF, xpB, Wh_f0, Wh_b0, x, H0);

    // layer 1 (input = H0, K = 256)
    gemm_bias_kernel<<<ggrid, 256, 0, stream>>>(H0, nullptr, Wx_f1, b_f1, xpF, 2 * H);
    gemm_bias_kernel<<<ggrid, 256, 0, stream>>>(H0, nullptr, Wx_b1, b_b1, xpB, 2 * H);
    lstm_scan_kernel<<<dim3(B, 2), 1024, 0, stream>>>(xpF, xpB, Wh_f1, Wh_b1, x, H1);

    // pooling + FC
    pool_kernel<<<BT / 4, 256, 0, stream>>>(H1, feat);
    fc_kernel<<<B, 128, 0, stream>>>(feat, fcW, fcb, out);
}